// Round 14
// baseline (315.106 us; speedup 1.0000x reference)
//
#include <hip/hip_runtime.h>
#include <stdint.h>

#define N 448
#define NN (N*N)          // 200704
#define P 128
#define H 64
#define PN 512            // padded row count for einsum operands
#define CH (PN*N)         // elements per channel matrix = 229376

typedef __attribute__((ext_vector_type(8))) short bf16x8;
typedef __attribute__((ext_vector_type(4))) float f32x4;
typedef __attribute__((ext_vector_type(16))) float f32x16;

__device__ __forceinline__ ushort f2bf(float f) {
    uint u = __builtin_bit_cast(uint, f);
    uint r = u + 0x7FFFu + ((u >> 16) & 1u);
    return (ushort)(r >> 16);
}
__device__ __forceinline__ float bf2f(ushort h) {
    uint u = ((uint)h) << 16;
    return __builtin_bit_cast(float, u);
}
__device__ __forceinline__ float sigmoidf(float x) {
    return 1.0f / (1.0f + __expf(-x));
}
// packed f32->bf16 RNE convert, 1 inst per 2 values (gfx950)
__device__ __forceinline__ uint cvtpk(float lo, float hi) {
    uint r;
    asm("v_cvt_pk_bf16_f32 %0, %1, %2" : "=v"(r) : "v"(lo), "v"(hi));
    return r;
}

// ---------------- kernel 0: weight prep ----------------
// wfrag layout: [(ct*4+ks)*64 + lane]*8 + b  holds Wcat[k][col], bf16
//   k = ks*32 + 8*(lane>>4) + b ; col = ct*16 + (lane&15)
// Wcat cols: 0-63 g1 | 64-127 l1 | 128-191 g2 | 192-255 l2 | 256-383 eg
__global__ void k_prep(const float* __restrict__ g1w, const float* __restrict__ l1w,
                       const float* __restrict__ g2w, const float* __restrict__ l2w,
                       const float* __restrict__ egw,
                       ushort* __restrict__ wfrag) {
    int idx = blockIdx.x*256 + threadIdx.x;
    for (int e = idx; e < 24*4*64*8; e += gridDim.x*256) {
        int b  = e & 7;
        int l  = (e >> 3) & 63;
        int ks = (e >> 9) & 3;
        int ct = e >> 11;
        int k   = ks*32 + 8*(l>>4) + b;
        int col = ct*16 + (l & 15);
        float v;
        if (col < 64)       v = g1w[k*64 + col];
        else if (col < 128) v = l1w[k*64 + col - 64];
        else if (col < 192) v = g2w[k*64 + col - 128];
        else if (col < 256) v = l2w[k*64 + col - 192];
        else                v = egw[k*128 + col - 256];
        wfrag[e] = f2bf(v);
    }
}

// ---------------- kernel 1: LN + projections, row-persistent (448 blocks x 7 j-tiles) ----------------
__global__ __launch_bounds__(256) void k_proj(
    const float* __restrict__ z, const float* __restrict__ mask,
    const float* __restrict__ lnw, const float* __restrict__ lnb,
    const float* __restrict__ g1b, const float* __restrict__ l1b,
    const float* __restrict__ g2b, const float* __restrict__ l2b,
    const float* __restrict__ egb,
    const ushort* __restrict__ wfrag,
    ushort* __restrict__ abt, ushort* __restrict__ gsig)
{
    __shared__ ushort zn[64*128];        // LN'ed tile, XOR-swizzled; reused as gs tile each iter
    __shared__ ushort abstage[128*72];   // ab tile [chan][j], rows padded to 72
    const int t = threadIdx.x;
    const int w = t >> 6, l = t & 63;
    const int i = blockIdx.x;

    const int p = t >> 2;          // 0..63 local position (LN mapping)
    const int q = t & 3;           // channel quarter
    const int half = w & 1, pair = w >> 1;
    const uint lr = l & 15, lk = l >> 4;
    const float* gb = pair ? g2b : g1b;
    const float* lb = pair ? l2b : l1b;

    // preload LN params (loop-invariant)
    float4 lwa[4], lwb[4], lba[4], lbb[4];
    #pragma unroll
    for (int cc = 0; cc < 4; ++cc) {
        int chunk = q*4 + cc;
        lwa[cc] = *(const float4*)(lnw + chunk*8);
        lwb[cc] = *(const float4*)(lnw + chunk*8 + 4);
        lba[cc] = *(const float4*)(lnb + chunk*8);
        lbb[cc] = *(const float4*)(lnb + chunk*8 + 4);
    }
    float egb0 = egb[w*32 + (int)lr];
    float egb1 = egb[w*32 + 16 + (int)lr];

    // prologue: load tile j=0
    float4 vA[8];
    {
        const float* zp = z + (size_t)(i*N + p)*P + q*32;
        #pragma unroll
        for (int x = 0; x < 8; ++x) vA[x] = *(const float4*)(zp + x*4);
    }

    #pragma unroll 1
    for (int jt = 0; jt < 7; ++jt) {
        const int j0 = jt*64;
        const float* mrow = mask + (size_t)i*N + j0;

        // --- LN of current tile -> zn ---
        {
            float s = 0.f, sq = 0.f;
            #pragma unroll
            for (int x = 0; x < 8; ++x) {
                s  += vA[x].x + vA[x].y + vA[x].z + vA[x].w;
                sq += vA[x].x*vA[x].x + vA[x].y*vA[x].y + vA[x].z*vA[x].z + vA[x].w*vA[x].w;
            }
            s += __shfl_xor(s, 1);  sq += __shfl_xor(sq, 1);
            s += __shfl_xor(s, 2);  sq += __shfl_xor(sq, 2);
            float mu   = s * (1.0f/128.0f);
            float var  = sq * (1.0f/128.0f) - mu*mu;
            float rstd = rsqrtf(var + 1e-5f);
            #pragma unroll
            for (int cc = 0; cc < 4; ++cc) {
                int chunk = q*4 + cc;
                float4 va = vA[cc*2], vb = vA[cc*2+1];
                float n0 = (va.x - mu)*rstd*lwa[cc].x + lba[cc].x;
                float n1 = (va.y - mu)*rstd*lwa[cc].y + lba[cc].y;
                float n2 = (va.z - mu)*rstd*lwa[cc].z + lba[cc].z;
                float n3 = (va.w - mu)*rstd*lwa[cc].w + lba[cc].w;
                float n4 = (vb.x - mu)*rstd*lwb[cc].x + lbb[cc].x;
                float n5 = (vb.y - mu)*rstd*lwb[cc].y + lbb[cc].y;
                float n6 = (vb.z - mu)*rstd*lwb[cc].z + lbb[cc].z;
                float n7 = (vb.w - mu)*rstd*lwb[cc].w + lbb[cc].w;
                uint4 pk;
                pk.x = cvtpk(n0, n1);
                pk.y = cvtpk(n2, n3);
                pk.z = cvtpk(n4, n5);
                pk.w = cvtpk(n6, n7);
                uint boff = (uint)p*256u + (((uint)(chunk ^ (p & 7)) & 15u) << 4);
                *(uint4*)((char*)zn + boff) = pk;
            }
        }
        // --- issue next tile's z loads; latency hides under this tile's MFMA phases ---
        if (jt < 6) {
            const float* zp = z + (size_t)(i*N + j0 + 64 + p)*P + q*32;
            #pragma unroll
            for (int x = 0; x < 8; ++x) vA[x] = *(const float4*)(zp + x*4);
        }
        __syncthreads();                       // bar1: zn ready

        float4 mv4[4];
        #pragma unroll
        for (int mi = 0; mi < 4; ++mi) mv4[mi] = *(const float4*)(mrow + mi*16 + (int)lk*4);

        // --- sub-passes (gate_s, lin_s) -> abstage ---
        #pragma unroll 1
        for (int sub = 0; sub < 2; ++sub) {
            const int ctg = pair*8 + half*2 + sub;
            const int ctl = ctg + 4;
            f32x4 ag[4], al[4];
            #pragma unroll
            for (int mi = 0; mi < 4; ++mi) { ag[mi] = (f32x4){0,0,0,0}; al[mi] = (f32x4){0,0,0,0}; }

            #pragma unroll
            for (int ks = 0; ks < 4; ++ks) {
                bf16x8 bg  = *(const bf16x8*)(wfrag + ((size_t)(ctg*4 + ks)*64 + l)*8);
                bf16x8 blf = *(const bf16x8*)(wfrag + ((size_t)(ctl*4 + ks)*64 + l)*8);
                #pragma unroll
                for (int mi = 0; mi < 4; ++mi) {
                    uint row = mi*16u + lr;
                    uint chunk = (uint)(ks*4) + lk;
                    bf16x8 af = *(const bf16x8*)((const char*)zn + row*256u + (((chunk ^ (row & 7u)) & 15u) << 4));
                    ag[mi] = __builtin_amdgcn_mfma_f32_16x16x32_bf16(af, bg,  ag[mi], 0,0,0);
                    al[mi] = __builtin_amdgcn_mfma_f32_16x16x32_bf16(af, blf, al[mi], 0,0,0);
                }
            }

            const int cidx = (half*2 + sub)*16 + (int)lr;
            const float gbias = gb[cidx];
            const float lbias = lb[cidx];
            const int srow = pair*64 + cidx;
            #pragma unroll
            for (int mi = 0; mi < 4; ++mi) {
                float4 mv = mv4[mi];
                float o0 = sigmoidf(ag[mi][0] + gbias) * (al[mi][0] + lbias) * mv.x;
                float o1 = sigmoidf(ag[mi][1] + gbias) * (al[mi][1] + lbias) * mv.y;
                float o2 = sigmoidf(ag[mi][2] + gbias) * (al[mi][2] + lbias) * mv.z;
                float o3 = sigmoidf(ag[mi][3] + gbias) * (al[mi][3] + lbias) * mv.w;
                uint2 pk;
                pk.x = cvtpk(o0, o1);
                pk.y = cvtpk(o2, o3);
                *(uint2*)(abstage + (size_t)srow*72 + mi*16 + (int)lk*4) = pk;
            }
        }
        __syncthreads();                       // bar2: abstage complete

        // --- coalesced ab flush: thread -> one 64B contiguous run in one channel plane ---
        {
            int r = t >> 1, hh2 = t & 1;
            const ushort* sp = abstage + (size_t)r*72 + hh2*32;
            ushort* dp = abt + (size_t)r*CH + (size_t)i*N + j0 + hh2*32;
            #pragma unroll
            for (int k2 = 0; k2 < 4; ++k2) {
                uint4 vv = *(const uint4*)(sp + k2*8);
                *(uint4*)(dp + k2*8) = vv;
            }
        }

        // --- eg sub-pass (reads zn) ---
        {
            f32x4 ae[4][2];
            #pragma unroll
            for (int mi = 0; mi < 4; ++mi) { ae[mi][0] = (f32x4){0,0,0,0}; ae[mi][1] = (f32x4){0,0,0,0}; }

            #pragma unroll
            for (int ks = 0; ks < 4; ++ks) {
                bf16x8 b0 = *(const bf16x8*)(wfrag + ((size_t)((16 + w*2)*4 + ks)*64 + l)*8);
                bf16x8 b1 = *(const bf16x8*)(wfrag + ((size_t)((17 + w*2)*4 + ks)*64 + l)*8);
                #pragma unroll
                for (int mi = 0; mi < 4; ++mi) {
                    uint row = mi*16u + lr;
                    uint chunk = (uint)(ks*4) + lk;
                    bf16x8 af = *(const bf16x8*)((const char*)zn + row*256u + (((chunk ^ (row & 7u)) & 15u) << 4));
                    ae[mi][0] = __builtin_amdgcn_mfma_f32_16x16x32_bf16(af, b0, ae[mi][0], 0,0,0);
                    ae[mi][1] = __builtin_amdgcn_mfma_f32_16x16x32_bf16(af, b1, ae[mi][1], 0,0,0);
                }
            }

            __syncthreads();                   // bar3: zn reads done -> reuse as gs tile

            #pragma unroll
            for (int mi = 0; mi < 4; ++mi) {
                float4 mv = mv4[mi];
                float mva[4] = { mv.x, mv.y, mv.z, mv.w };
                #pragma unroll
                for (int e = 0; e < 2; ++e) {
                    uint cg = (uint)(w*32 + e*16) + lr;
                    float bias = e ? egb1 : egb0;
                    #pragma unroll
                    for (int r = 0; r < 4; ++r) {
                        float sg = sigmoidf(ae[mi][e][r] + bias) * mva[r];   // mask folded in
                        uint row = (uint)(mi*16) + lk*4u + (uint)r;
                        uint boff = row*256u + (((((cg >> 3) ^ (row & 7u)) & 15u)) << 4) + ((cg & 7u) << 1);
                        *(ushort*)((char*)zn + boff) = (ushort)cvtpk(sg, sg);
                    }
                }
            }
        }
        __syncthreads();                       // bar4: gs tile ready

        // coalesced gsig store: thread covers 32 channels of one position
        {
            size_t pos = (size_t)(i*N + j0 + p);
            #pragma unroll
            for (int s2 = 0; s2 < 4; ++s2) {
                int chunk = q*4 + s2;
                uint boff = (uint)p*256u + (((uint)(chunk ^ (p & 7)) & 15u) << 4);
                uint4 vv = *(const uint4*)((const char*)zn + boff);
                *(uint4*)(gsig + pos*128 + q*32 + s2*8) = vv;
            }
        }
        __syncthreads();                       // bar5: gs reads done before next LN overwrites zn
    }
}

// ---------------- kernel 2: per-channel transpose [c][i][k] -> [c][k][i] ----------------
__global__ __launch_bounds__(256) void k_transpose(const ushort* __restrict__ abt,
                                                   ushort* __restrict__ abtt) {
    int bid = blockIdx.x;
    int tile = bid % 49, a = bid / 49;              // a in 0..127 (both arrays)
    int y0 = (tile / 7) * 64, x0 = (tile % 7) * 64;
    const ushort* src = abt  + (size_t)a*CH;
    ushort*       dst = abtt + (size_t)a*CH;
    __shared__ ushort tl[64][68];
    int t = threadIdx.x;
    #pragma unroll
    for (int q = 0; q < 4; ++q) {
        int f = q*1024 + t*4;
        int r = f >> 6, c4 = f & 63;
        ushort4 v = *(const ushort4*)(src + (size_t)(y0 + r)*N + x0 + c4);
        tl[r][c4] = v.x; tl[r][c4+1] = v.y; tl[r][c4+2] = v.z; tl[r][c4+3] = v.w;
    }
    __syncthreads();
    #pragma unroll
    for (int q = 0; q < 4; ++q) {
        int f = q*1024 + t*4;
        int r = f >> 6, c4 = f & 63;
        ushort4 v;
        v.x = tl[c4][r]; v.y = tl[c4+1][r]; v.z = tl[c4+2][r]; v.w = tl[c4+3][r];
        *(ushort4*)(dst + (size_t)(x0 + r)*N + y0 + c4) = v;
    }
}

// ---------------- kernel 3: triangle einsums (batched NT GEMMs, 32x32x16 bf16 MFMA) ----------------
__global__ __launch_bounds__(256) void k_tri(const ushort* __restrict__ abt,
                                             const ushort* __restrict__ abtt,
                                             float* __restrict__ blk) {
    int bid = (blockIdx.x & 7)*128 + (blockIdx.x >> 3);
    const int c = bid >> 4;
    const int tij = bid & 15;
    const int i0 = (tij >> 2) * 128, j0 = (tij & 3) * 128;
    const int t = threadIdx.x, w = t >> 6, l = t & 63;
    const int wr = w >> 1, wc = w & 1;
    const uint l31 = l & 31, kg = (uint)l >> 5;   // 32x32 fragment coords

    __shared__ ushort lds[4][128*64];   // tA1, tA2, tT1, tT2 ; rows XOR-chunk swizzled

    const ushort* basep = (w >= 2) ? abtt : abt;
    const int chan = (w & 1) ? 64 + c : c;
    const int r0   = (w & 1) ? j0 : i0;
    const ushort* sbase = basep + (size_t)chan*CH + (size_t)r0*N;

    f32x16 acc[2][2];
    #pragma unroll
    for (int a = 0; a < 2; ++a)
        #pragma unroll
        for (int b = 0; b < 2; ++b) acc[a][b] = (f32x16){0,0,0,0,0,0,0,0,0,0,0,0,0,0,0,0};

    for (int kk = 0; kk < 7; ++kk) {
        __syncthreads();
        const ushort* sb = sbase + kk*64;
        #pragma unroll
        for (int q = 0; q < 16; ++q) {
            int r  = q*8 + (l >> 3);
            int ch = (l & 7) ^ (r & 7);
            const ushort* g = sb + (size_t)r*N + ch*8;
            __builtin_amdgcn_global_load_lds(
                (const __attribute__((address_space(1))) uint*)g,
                (__attribute__((address_space(3))) uint*)(&lds[w][q*512]),
                16, 0, 0);
        }
        __syncthreads();

        #pragma unroll
        for (int ks = 0; ks < 4; ++ks) {
            const uint chunk = (uint)(ks*2) + kg;
            {
                bf16x8 aA[2], bB[2];
                #pragma unroll
                for (int x = 0; x < 2; ++x) {
                    uint rowa = (uint)wr*64u + (uint)x*32u + l31;
                    uint rowb = (uint)wc*64u + (uint)x*32u + l31;
                    aA[x] = *(const bf16x8*)((const char*)lds[0] + rowa*128u + (((chunk ^ (rowa & 7u)) & 15u) << 4));
                    bB[x] = *(const bf16x8*)((const char*)lds[1] + rowb*128u + (((chunk ^ (rowb & 7u)) & 15u) << 4));
                }
                #pragma unroll
                for (int ra = 0; ra < 2; ++ra)
                    #pragma unroll
                    for (int cb = 0; cb < 2; ++cb)
                        acc[ra][cb] = __builtin_amdgcn_mfma_f32_32x32x16_bf16(aA[ra], bB[cb], acc[ra][cb], 0,0,0);
            }
            {
                bf16x8 aA[2], bB[2];
                #pragma unroll
                for (int x = 0; x < 2; ++x) {
                    uint rowa = (uint)wr*64u + (uint)x*32u + l31;
                    uint rowb = (uint)wc*64u + (uint)x*32u + l31;
                    aA[x] = *(const bf16x8*)((const char*)lds[2] + rowa*128u + (((chunk ^ (rowa & 7u)) & 15u) << 4));
                    bB[x] = *(const bf16x8*)((const char*)lds[3] + rowb*128u + (((chunk ^ (rowb & 7u)) & 15u) << 4));
                }
                #pragma unroll
                for (int ra = 0; ra < 2; ++ra)
                    #pragma unroll
                    for (int cb = 0; cb < 2; ++cb)
                        acc[ra][cb] = __builtin_amdgcn_mfma_f32_32x32x16_bf16(aA[ra], bB[cb], acc[ra][cb], 0,0,0);
            }
        }
    }

    // D layout (32x32): col = lane&31, row = (reg&3) + 8*(reg>>2) + 4*(lane>>5)
    #pragma unroll
    for (int ra = 0; ra < 2; ++ra) {
        #pragma unroll
        for (int cb = 0; cb < 2; ++cb) {
            int jb = j0 + wc*64 + cb*32 + (int)l31;
            if (jb < N) {
                #pragma unroll
                for (int r = 0; r < 16; ++r) {
                    int ii = i0 + wr*64 + ra*32 + (r & 3) + 8*(r >> 2) + 4*(int)kg;
                    if (ii < N) blk[(size_t)c*NN + (size_t)ii*N + jb] = acc[ra][cb][r];
                }
            }
        }
    }
}

// ---------------- kernel 4: LN(block) @ out_w, 4 tiles/block, prefetch-pipelined ----------------
__global__ __launch_bounds__(256) void k_out(const float* __restrict__ blk,
    const ushort* __restrict__ gsig,
    const float* __restrict__ lnhw, const float* __restrict__ lnhb,
    const float* __restrict__ outw, const float* __restrict__ outb,
    float* __restrict__ out)
{
    __shared__ float sblk[2][64][68];
    const int t = threadIdx.x;
    const int w = t >> 6, l = t & 63;
    const int base = blockIdx.x * 256;   // 4 tiles of 64 positions

    float4 pre[4];
    #pragma unroll
    for (int qq = 0; qq < 4; ++qq) {
        int flat = qq*256 + t;
        int h = flat >> 4, f4 = flat & 15;
        pre[qq] = *(const float4*)(blk + (size_t)h*NN + base + f4*4);
    }

    #pragma unroll 1
    for (int tt = 0; tt < 4; ++tt) {
        const int b = tt & 1;
        const int pos0 = base + tt*64;

        #pragma unroll
        for (int qq = 0; qq < 4; ++qq) {
            int flat = qq*256 + t;
            int h = flat >> 4, f4 = flat & 15;
            sblk[b][f4*4+0][h] = pre[qq].x;
            sblk[b][f4*4+1][h] = pre[qq].y;
            sblk[b][f4*4+2][h] = pre[qq].z;
            sblk[b][f4*4+3][h] = pre[qq].w;
        }
        if (tt < 3) {
            #pragma unroll
            for (int qq = 0; qq < 4; ++qq) {
                int flat = qq*256 + t;
                int h = flat >> 4, f4 = flat & 15;
                pre[qq] = *(const float4*)(blk + (size_t)h*NN + pos0 + 64 + f4*4);
            }
        }
        __syncthreads();

        {
            int p = w*16 + (l >> 2);
            int sub = l & 3;
            float vv[16];
            float s = 0.f, sq = 0.f;
            #pragma unroll
            for (int j = 0; j < 16; ++j) {
                float x = sblk[b][p][sub*16 + j];
                vv[j] = x; s += x; sq += x*x;
            }
            s += __shfl_xor(s, 1);  sq += __shfl_xor(sq, 1);
            s += __shfl_xor(s, 2);  sq += __shfl_xor(sq, 2);
            float mu   = s * (1.0f/64.0f);
            float var  = sq * (1.0f/64.0f) - mu*mu;
            float rstd = rsqrtf(var + 1e-5f);
            #pragma unroll
            for (int j = 0; j < 16; ++j) {
                float nv = (vv[j] - mu)*rstd*lnhw[sub*16+j] + lnhb[sub*16+j];
                sblk[b][p][sub*16 + j] = nv;
            }
        }
        __syncthreads();

        const int c4 = (t & 31) * 4;
        const int pg = t >> 5;
        float4 ob = *(const float4*)(outb + c4);

        #pragma unroll 1
        for (int hh = 0; hh < 2; ++hh) {
            const int prow = hh*32 + pg*4;
            float acc[4][4];
            #pragma unroll
            for (int j2 = 0; j2 < 4; ++j2)
                #pragma unroll
                for (int cc = 0; cc < 4; ++cc) acc[j2][cc] = 0.f;

            #pragma unroll 4
            for (int h4 = 0; h4 < 16; ++h4) {
                float4 wv[4];
                #pragma unroll
                for (int j = 0; j < 4; ++j)
                    wv[j] = *(const float4*)(outw + (h4*4+j)*128 + c4);
                #pragma unroll
                for (int j2 = 0; j2 < 4; ++j2) {
                    float4 av = *(const float4*)(&sblk[b][prow + j2][h4*4]);
                    acc[j2][0] += av.x*wv[0].x + av.y*wv[1].x + av.z*wv[2].x + av.w*wv[3].x;
                    acc[j2][1] += av.x*wv[0].y + av.y*wv[1].y + av.z*wv[2].y + av.w*wv[3].y;
                    acc[j2][2] += av.x*wv[0].z + av.y*wv[1].z + av.z*wv[2].z + av.w*wv[3].z;
                    acc[j2][3] += av.x*wv[0].w + av.y*wv[1].w + av.z*wv[2].w + av.w*wv[3].w;
                }
            }

            #pragma unroll
            for (int j2 = 0; j2 < 4; ++j2) {
                size_t pos = (size_t)(pos0 + prow + j2);
                ushort4 gv = *(const ushort4*)(gsig + pos*128 + c4);
                float4 res;
                res.x = bf2f(gv.x) * (acc[j2][0] + ob.x);
                res.y = bf2f(gv.y) * (acc[j2][1] + ob.y);
                res.z = bf2f(gv.z) * (acc[j2][2] + ob.z);
                res.w = bf2f(gv.w) * (acc[j2][3] + ob.w);
                *(float4*)(out + pos*128 + c4) = res;
            }
        }
    }
}

extern "C" void kernel_launch(void* const* d_in, const int* in_sizes, int n_in,
                              void* d_out, int out_size, void* d_ws, size_t ws_size,
                              hipStream_t stream) {
    const float* z    = (const float*)d_in[0];
    const float* mask = (const float*)d_in[1];
    const float* lnw  = (const float*)d_in[2];
    const float* lnb  = (const float*)d_in[3];
    const float* lnhw = (const float*)d_in[4];
    const float* lnhb = (const float*)d_in[5];
    const float* g1w  = (const float*)d_in[6];
    const float* g1b  = (const float*)d_in[7];
    const float* g2w  = (const float*)d_in[8];
    const float* g2b  = (const float*)d_in[9];
    const float* l1w  = (const float*)d_in[10];
    const float* l1b  = (const float*)d_in[11];
    const float* l2w  = (const float*)d_in[12];
    const float* l2b  = (const float*)d_in[13];
    const float* egw  = (const float*)d_in[14];
    const float* egb  = (const float*)d_in[15];
    const float* outw = (const float*)d_in[16];
    const float* outb = (const float*)d_in[17];

    char* ws = (char*)d_ws;
    const size_t SZ_AB = (size_t)2*64*CH*2;          // 58,720,256 B (ab1+ab2, padded rows)
    const size_t SZ_G  = (size_t)NN*128*2;           // 51,380,224 B
    const size_t SZ_BL = (size_t)64*NN*4;            // 51,380,224 B
    ushort* abt    = (ushort*)ws;
    ushort* abtt   = (ushort*)(ws + SZ_AB);
    ushort* gsig   = (ushort*)(ws + 2*SZ_AB);
    float*  blkb   = (float*) (ws + 2*SZ_AB + SZ_G);
    ushort* wfrag  = (ushort*)(ws + 2*SZ_AB + SZ_G + SZ_BL);

    k_prep<<<32, 256, 0, stream>>>(g1w, l1w, g2w, l2w, egw, wfrag);
    k_proj<<<448, 256, 0, stream>>>(z, mask, lnw, lnb, g1b, l1b, g2b, l2b, egb, wfrag, abt, gsig);
    k_transpose<<<128*49, 256, 0, stream>>>(abt, abtt);
    k_tri<<<64*16, 256, 0, stream>>>(abt, abtt, blkb);
    k_out<<<NN/256, 256, 0, stream>>>(blkb, gsig, lnhw, lnhb, outw, outb, (float*)d_out);
}

// Round 15
// 300.031 us; speedup vs baseline: 1.0502x; 1.0502x over previous
//
#include <hip/hip_runtime.h>
#include <stdint.h>

#define N 448
#define NN (N*N)          // 200704
#define P 128
#define H 64
#define PN 512            // padded row count for einsum operands
#define CH (PN*N)         // elements per channel matrix = 229376

typedef __attribute__((ext_vector_type(8))) short bf16x8;
typedef __attribute__((ext_vector_type(4))) float f32x4;
typedef __attribute__((ext_vector_type(16))) float f32x16;

__device__ __forceinline__ ushort f2bf(float f) {
    uint u = __builtin_bit_cast(uint, f);
    uint r = u + 0x7FFFu + ((u >> 16) & 1u);
    return (ushort)(r >> 16);
}
__device__ __forceinline__ float bf2f(ushort h) {
    uint u = ((uint)h) << 16;
    return __builtin_bit_cast(float, u);
}
__device__ __forceinline__ float sigmoidf(float x) {
    return 1.0f / (1.0f + __expf(-x));
}
// packed f32->bf16 RNE convert, 1 inst per 2 values (gfx950)
__device__ __forceinline__ uint cvtpk(float lo, float hi) {
    uint r;
    asm("v_cvt_pk_bf16_f32 %0, %1, %2" : "=v"(r) : "v"(lo), "v"(hi));
    return r;
}

// ---------------- kernel 0: weight prep ----------------
// wfrag layout: [(ct*4+ks)*64 + lane]*8 + b  holds Wcat[k][col], bf16
//   k = ks*32 + 8*(lane>>4) + b ; col = ct*16 + (lane&15)
// Wcat cols: 0-63 g1 | 64-127 l1 | 128-191 g2 | 192-255 l2 | 256-383 eg
__global__ void k_prep(const float* __restrict__ g1w, const float* __restrict__ l1w,
                       const float* __restrict__ g2w, const float* __restrict__ l2w,
                       const float* __restrict__ egw,
                       ushort* __restrict__ wfrag) {
    int idx = blockIdx.x*256 + threadIdx.x;
    for (int e = idx; e < 24*4*64*8; e += gridDim.x*256) {
        int b  = e & 7;
        int l  = (e >> 3) & 63;
        int ks = (e >> 9) & 3;
        int ct = e >> 11;
        int k   = ks*32 + 8*(l>>4) + b;
        int col = ct*16 + (l & 15);
        float v;
        if (col < 64)       v = g1w[k*64 + col];
        else if (col < 128) v = l1w[k*64 + col - 64];
        else if (col < 192) v = g2w[k*64 + col - 128];
        else if (col < 256) v = l2w[k*64 + col - 192];
        else                v = egw[k*128 + col - 256];
        wfrag[e] = f2bf(v);
    }
}

// ---------------- kernel 1: LN + projections, 1-WAVE blocks (32 pos/wave, no barriers) ----------------
__global__ __launch_bounds__(64) void k_proj(
    const float* __restrict__ z, const float* __restrict__ mask,
    const float* __restrict__ lnw, const float* __restrict__ lnb,
    const float* __restrict__ g1b, const float* __restrict__ l1b,
    const float* __restrict__ g2b, const float* __restrict__ l2b,
    const float* __restrict__ egb,
    const ushort* __restrict__ wfrag,
    ushort* __restrict__ abt, ushort* __restrict__ gsig)
{
    __shared__ ushort zn[32*128];   // 8 KB: LN'ed tile (XOR-swizzled); reused as gs tile
    const int l = threadIdx.x;
    const int bid = blockIdx.x;
    const int i = bid / 14, j0 = (bid % 14) * 32;
    const uint lr = l & 15, lk = (uint)l >> 4;
    const int pp = l >> 2;          // 0..15 pos offset within LN pass
    const int pq = l & 3;           // channel quarter

    // --- LN: two passes of 16 positions each ---
    #pragma unroll 1
    for (int px = 0; px < 2; ++px) {
        int p = px*16 + pp;
        const float* zp = z + (size_t)(i*N + j0 + p)*P + pq*32;
        float4 v[8];
        #pragma unroll
        for (int x = 0; x < 8; ++x) v[x] = *(const float4*)(zp + x*4);
        float s = 0.f, sq = 0.f;
        #pragma unroll
        for (int x = 0; x < 8; ++x) {
            s  += v[x].x + v[x].y + v[x].z + v[x].w;
            sq += v[x].x*v[x].x + v[x].y*v[x].y + v[x].z*v[x].z + v[x].w*v[x].w;
        }
        s += __shfl_xor(s, 1);  sq += __shfl_xor(sq, 1);
        s += __shfl_xor(s, 2);  sq += __shfl_xor(sq, 2);
        float mu   = s * (1.0f/128.0f);
        float var  = sq * (1.0f/128.0f) - mu*mu;
        float rstd = rsqrtf(var + 1e-5f);
        #pragma unroll
        for (int cc = 0; cc < 4; ++cc) {
            int chunk = pq*4 + cc;
            const float* lwp = lnw + chunk*8;
            const float* lbp = lnb + chunk*8;
            float4 lwa = *(const float4*)(lwp), lwb = *(const float4*)(lwp+4);
            float4 lba = *(const float4*)(lbp), lbb = *(const float4*)(lbp+4);
            float4 va = v[cc*2], vb = v[cc*2+1];
            float n0 = (va.x - mu)*rstd*lwa.x + lba.x;
            float n1 = (va.y - mu)*rstd*lwa.y + lba.y;
            float n2 = (va.z - mu)*rstd*lwa.z + lba.z;
            float n3 = (va.w - mu)*rstd*lwa.w + lba.w;
            float n4 = (vb.x - mu)*rstd*lwb.x + lbb.x;
            float n5 = (vb.y - mu)*rstd*lwb.y + lbb.y;
            float n6 = (vb.z - mu)*rstd*lwb.z + lbb.z;
            float n7 = (vb.w - mu)*rstd*lwb.w + lbb.w;
            uint4 pk;
            pk.x = cvtpk(n0, n1);
            pk.y = cvtpk(n2, n3);
            pk.z = cvtpk(n4, n5);
            pk.w = cvtpk(n6, n7);
            uint boff = (uint)p*256u + (((uint)(chunk ^ (p & 7)) & 15u) << 4);
            *(uint4*)((char*)zn + boff) = pk;
        }
    }
    __syncthreads();   // 1-wave: just drains LDS writes before cross-lane reads

    // --- preload all A-fragments into registers (frees zn for gs reuse) ---
    bf16x8 af[2][4];
    #pragma unroll
    for (int mi = 0; mi < 2; ++mi) {
        uint row = (uint)mi*16u + lr;
        #pragma unroll
        for (int ks = 0; ks < 4; ++ks) {
            uint chunk = (uint)(ks*4) + lk;
            af[mi][ks] = *(const bf16x8*)((const char*)zn + row*256u + (((chunk ^ (row & 7u)) & 15u) << 4));
        }
    }

    // mask values for this wave's output rows
    float4 mv4[2];
    #pragma unroll
    for (int mi = 0; mi < 2; ++mi)
        mv4[mi] = *(const float4*)(mask + (size_t)i*N + j0 + mi*16 + (int)lk*4);

    // --- ab sub-passes: pair x sub, 2 tiles each, 16 acc regs live ---
    #pragma unroll 1
    for (int pair = 0; pair < 2; ++pair) {
        const float* gbp = pair ? g2b : g1b;
        const float* lbp = pair ? l2b : l1b;
        #pragma unroll 1
        for (int sub = 0; sub < 4; ++sub) {
            const int ctg = pair*8 + sub;
            const int ctl = ctg + 4;
            f32x4 ag[2], al[2];
            ag[0] = (f32x4){0,0,0,0}; ag[1] = (f32x4){0,0,0,0};
            al[0] = (f32x4){0,0,0,0}; al[1] = (f32x4){0,0,0,0};
            #pragma unroll
            for (int ks = 0; ks < 4; ++ks) {
                bf16x8 bg  = *(const bf16x8*)(wfrag + ((size_t)(ctg*4 + ks)*64 + l)*8);
                bf16x8 blf = *(const bf16x8*)(wfrag + ((size_t)(ctl*4 + ks)*64 + l)*8);
                #pragma unroll
                for (int mi = 0; mi < 2; ++mi) {
                    ag[mi] = __builtin_amdgcn_mfma_f32_16x16x32_bf16(af[mi][ks], bg,  ag[mi], 0,0,0);
                    al[mi] = __builtin_amdgcn_mfma_f32_16x16x32_bf16(af[mi][ks], blf, al[mi], 0,0,0);
                }
            }
            const int cidx = sub*16 + (int)lr;     // 0..63 within ab
            const float gbias = gbp[cidx];
            const float lbias = lbp[cidx];
            #pragma unroll
            for (int mi = 0; mi < 2; ++mi) {
                float4 mv = mv4[mi];
                float o0 = sigmoidf(ag[mi][0] + gbias) * (al[mi][0] + lbias) * mv.x;
                float o1 = sigmoidf(ag[mi][1] + gbias) * (al[mi][1] + lbias) * mv.y;
                float o2 = sigmoidf(ag[mi][2] + gbias) * (al[mi][2] + lbias) * mv.z;
                float o3 = sigmoidf(ag[mi][3] + gbias) * (al[mi][3] + lbias) * mv.w;
                uint2 pk;
                pk.x = cvtpk(o0, o1);
                pk.y = cvtpk(o2, o3);
                size_t off = (size_t)(pair*64 + cidx)*CH + (size_t)i*N + j0 + mi*16 + (int)lk*4;
                *(uint2*)(abt + off) = pk;   // background store; no barrier will drain it
            }
        }
    }

    // --- eg sub-passes -> gs values into zn (A-frags already in regs) ---
    #pragma unroll 1
    for (int es = 0; es < 4; ++es) {
        const int ct0 = 16 + es*2;
        f32x4 ae0[2], ae1[2];
        ae0[0] = (f32x4){0,0,0,0}; ae0[1] = (f32x4){0,0,0,0};
        ae1[0] = (f32x4){0,0,0,0}; ae1[1] = (f32x4){0,0,0,0};
        #pragma unroll
        for (int ks = 0; ks < 4; ++ks) {
            bf16x8 b0 = *(const bf16x8*)(wfrag + ((size_t)(ct0*4 + ks)*64 + l)*8);
            bf16x8 b1 = *(const bf16x8*)(wfrag + ((size_t)((ct0+1)*4 + ks)*64 + l)*8);
            #pragma unroll
            for (int mi = 0; mi < 2; ++mi) {
                ae0[mi] = __builtin_amdgcn_mfma_f32_16x16x32_bf16(af[mi][ks], b0, ae0[mi], 0,0,0);
                ae1[mi] = __builtin_amdgcn_mfma_f32_16x16x32_bf16(af[mi][ks], b1, ae1[mi], 0,0,0);
            }
        }
        float bias0 = egb[es*32 + (int)lr];
        float bias1 = egb[es*32 + 16 + (int)lr];
        #pragma unroll
        for (int mi = 0; mi < 2; ++mi) {
            float4 mv = mv4[mi];
            float mva[4] = { mv.x, mv.y, mv.z, mv.w };
            #pragma unroll
            for (int e = 0; e < 2; ++e) {
                uint cg = (uint)(es*32 + e*16) + lr;   // 0..127
                float bias = e ? bias1 : bias0;
                const f32x4* aep = e ? &ae1[mi] : &ae0[mi];
                #pragma unroll
                for (int r = 0; r < 4; ++r) {
                    float sg = sigmoidf((*aep)[r] + bias) * mva[r];   // mask folded in
                    uint row = (uint)(mi*16) + lk*4u + (uint)r;
                    uint boff = row*256u + (((((cg >> 3) ^ (row & 7u)) & 15u)) << 4) + ((cg & 7u) << 1);
                    *(ushort*)((char*)zn + boff) = (ushort)cvtpk(sg, sg);
                }
            }
        }
    }
    __syncthreads();   // drain gs LDS writes before cross-lane reads

    // --- coalesced gsig store: lane covers 32 channels of one position, 2 passes ---
    #pragma unroll
    for (int px = 0; px < 2; ++px) {
        int p = px*16 + pp;
        size_t pos = (size_t)(i*N + j0 + p);
        #pragma unroll
        for (int s2 = 0; s2 < 4; ++s2) {
            int chunk = pq*4 + s2;
            uint boff = (uint)p*256u + (((uint)(chunk ^ (p & 7)) & 15u) << 4);
            uint4 vv = *(const uint4*)((const char*)zn + boff);
            *(uint4*)(gsig + pos*128 + pq*32 + s2*8) = vv;
        }
    }
}

// ---------------- kernel 2: per-channel transpose [c][i][k] -> [c][k][i] ----------------
__global__ __launch_bounds__(256) void k_transpose(const ushort* __restrict__ abt,
                                                   ushort* __restrict__ abtt) {
    int bid = blockIdx.x;
    int tile = bid % 49, a = bid / 49;              // a in 0..127 (both arrays)
    int y0 = (tile / 7) * 64, x0 = (tile % 7) * 64;
    const ushort* src = abt  + (size_t)a*CH;
    ushort*       dst = abtt + (size_t)a*CH;
    __shared__ ushort tl[64][68];
    int t = threadIdx.x;
    #pragma unroll
    for (int q = 0; q < 4; ++q) {
        int f = q*1024 + t*4;
        int r = f >> 6, c4 = f & 63;
        ushort4 v = *(const ushort4*)(src + (size_t)(y0 + r)*N + x0 + c4);
        tl[r][c4] = v.x; tl[r][c4+1] = v.y; tl[r][c4+2] = v.z; tl[r][c4+3] = v.w;
    }
    __syncthreads();
    #pragma unroll
    for (int q = 0; q < 4; ++q) {
        int f = q*1024 + t*4;
        int r = f >> 6, c4 = f & 63;
        ushort4 v;
        v.x = tl[c4][r]; v.y = tl[c4+1][r]; v.z = tl[c4+2][r]; v.w = tl[c4+3][r];
        *(ushort4*)(dst + (size_t)(x0 + r)*N + y0 + c4) = v;
    }
}

// ---------------- kernel 3: triangle einsums (batched NT GEMMs, 32x32x16 bf16 MFMA) ----------------
__global__ __launch_bounds__(256) void k_tri(const ushort* __restrict__ abt,
                                             const ushort* __restrict__ abtt,
                                             float* __restrict__ blk) {
    int bid = (blockIdx.x & 7)*128 + (blockIdx.x >> 3);
    const int c = bid >> 4;
    const int tij = bid & 15;
    const int i0 = (tij >> 2) * 128, j0 = (tij & 3) * 128;
    const int t = threadIdx.x, w = t >> 6, l = t & 63;
    const int wr = w >> 1, wc = w & 1;
    const uint l31 = l & 31, kg = (uint)l >> 5;   // 32x32 fragment coords

    __shared__ ushort lds[4][128*64];   // tA1, tA2, tT1, tT2 ; rows XOR-chunk swizzled

    const ushort* basep = (w >= 2) ? abtt : abt;
    const int chan = (w & 1) ? 64 + c : c;
    const int r0   = (w & 1) ? j0 : i0;
    const ushort* sbase = basep + (size_t)chan*CH + (size_t)r0*N;

    f32x16 acc[2][2];
    #pragma unroll
    for (int a = 0; a < 2; ++a)
        #pragma unroll
        for (int b = 0; b < 2; ++b) acc[a][b] = (f32x16){0,0,0,0,0,0,0,0,0,0,0,0,0,0,0,0};

    for (int kk = 0; kk < 7; ++kk) {
        __syncthreads();
        const ushort* sb = sbase + kk*64;
        #pragma unroll
        for (int q = 0; q < 16; ++q) {
            int r  = q*8 + (l >> 3);
            int ch = (l & 7) ^ (r & 7);
            const ushort* g = sb + (size_t)r*N + ch*8;
            __builtin_amdgcn_global_load_lds(
                (const __attribute__((address_space(1))) uint*)g,
                (__attribute__((address_space(3))) uint*)(&lds[w][q*512]),
                16, 0, 0);
        }
        __syncthreads();

        #pragma unroll
        for (int ks = 0; ks < 4; ++ks) {
            const uint chunk = (uint)(ks*2) + kg;
            {
                bf16x8 aA[2], bB[2];
                #pragma unroll
                for (int x = 0; x < 2; ++x) {
                    uint rowa = (uint)wr*64u + (uint)x*32u + l31;
                    uint rowb = (uint)wc*64u + (uint)x*32u + l31;
                    aA[x] = *(const bf16x8*)((const char*)lds[0] + rowa*128u + (((chunk ^ (rowa & 7u)) & 15u) << 4));
                    bB[x] = *(const bf16x8*)((const char*)lds[1] + rowb*128u + (((chunk ^ (rowb & 7u)) & 15u) << 4));
                }
                #pragma unroll
                for (int ra = 0; ra < 2; ++ra)
                    #pragma unroll
                    for (int cb = 0; cb < 2; ++cb)
                        acc[ra][cb] = __builtin_amdgcn_mfma_f32_32x32x16_bf16(aA[ra], bB[cb], acc[ra][cb], 0,0,0);
            }
            {
                bf16x8 aA[2], bB[2];
                #pragma unroll
                for (int x = 0; x < 2; ++x) {
                    uint rowa = (uint)wr*64u + (uint)x*32u + l31;
                    uint rowb = (uint)wc*64u + (uint)x*32u + l31;
                    aA[x] = *(const bf16x8*)((const char*)lds[2] + rowa*128u + (((chunk ^ (rowa & 7u)) & 15u) << 4));
                    bB[x] = *(const bf16x8*)((const char*)lds[3] + rowb*128u + (((chunk ^ (rowb & 7u)) & 15u) << 4));
                }
                #pragma unroll
                for (int ra = 0; ra < 2; ++ra)
                    #pragma unroll
                    for (int cb = 0; cb < 2; ++cb)
                        acc[ra][cb] = __builtin_amdgcn_mfma_f32_32x32x16_bf16(aA[ra], bB[cb], acc[ra][cb], 0,0,0);
            }
        }
    }

    // D layout (32x32): col = lane&31, row = (reg&3) + 8*(reg>>2) + 4*(lane>>5)
    #pragma unroll
    for (int ra = 0; ra < 2; ++ra) {
        #pragma unroll
        for (int cb = 0; cb < 2; ++cb) {
            int jb = j0 + wc*64 + cb*32 + (int)l31;
            if (jb < N) {
                #pragma unroll
                for (int r = 0; r < 16; ++r) {
                    int ii = i0 + wr*64 + ra*32 + (r & 3) + 8*(r >> 2) + 4*(int)kg;
                    if (ii < N) blk[(size_t)c*NN + (size_t)ii*N + jb] = acc[ra][cb][r];
                }
            }
        }
    }
}

// ---------------- kernel 4: LN(block) @ out_w, 4 tiles/block, prefetch-pipelined ----------------
__global__ __launch_bounds__(256) void k_out(const float* __restrict__ blk,
    const ushort* __restrict__ gsig,
    const float* __restrict__ lnhw, const float* __restrict__ lnhb,
    const float* __restrict__ outw, const float* __restrict__ outb,
    float* __restrict__ out)
{
    __shared__ float sblk[2][64][68];
    const int t = threadIdx.x;
    const int w = t >> 6, l = t & 63;
    const int base = blockIdx.x * 256;   // 4 tiles of 64 positions

    float4 pre[4];
    #pragma unroll
    for (int qq = 0; qq < 4; ++qq) {
        int flat = qq*256 + t;
        int h = flat >> 4, f4 = flat & 15;
        pre[qq] = *(const float4*)(blk + (size_t)h*NN + base + f4*4);
    }

    #pragma unroll 1
    for (int tt = 0; tt < 4; ++tt) {
        const int b = tt & 1;
        const int pos0 = base + tt*64;

        #pragma unroll
        for (int qq = 0; qq < 4; ++qq) {
            int flat = qq*256 + t;
            int h = flat >> 4, f4 = flat & 15;
            sblk[b][f4*4+0][h] = pre[qq].x;
            sblk[b][f4*4+1][h] = pre[qq].y;
            sblk[b][f4*4+2][h] = pre[qq].z;
            sblk[b][f4*4+3][h] = pre[qq].w;
        }
        if (tt < 3) {
            #pragma unroll
            for (int qq = 0; qq < 4; ++qq) {
                int flat = qq*256 + t;
                int h = flat >> 4, f4 = flat & 15;
                pre[qq] = *(const float4*)(blk + (size_t)h*NN + pos0 + 64 + f4*4);
            }
        }
        __syncthreads();

        {
            int p = w*16 + (l >> 2);
            int sub = l & 3;
            float vv[16];
            float s = 0.f, sq = 0.f;
            #pragma unroll
            for (int j = 0; j < 16; ++j) {
                float x = sblk[b][p][sub*16 + j];
                vv[j] = x; s += x; sq += x*x;
            }
            s += __shfl_xor(s, 1);  sq += __shfl_xor(sq, 1);
            s += __shfl_xor(s, 2);  sq += __shfl_xor(sq, 2);
            float mu   = s * (1.0f/64.0f);
            float var  = sq * (1.0f/64.0f) - mu*mu;
            float rstd = rsqrtf(var + 1e-5f);
            #pragma unroll
            for (int j = 0; j < 16; ++j) {
                float nv = (vv[j] - mu)*rstd*lnhw[sub*16+j] + lnhb[sub*16+j];
                sblk[b][p][sub*16 + j] = nv;
            }
        }
        __syncthreads();

        const int c4 = (t & 31) * 4;
        const int pg = t >> 5;
        float4 ob = *(const float4*)(outb + c4);

        #pragma unroll 1
        for (int hh = 0; hh < 2; ++hh) {
            const int prow = hh*32 + pg*4;
            float acc[4][4];
            #pragma unroll
            for (int j2 = 0; j2 < 4; ++j2)
                #pragma unroll
                for (int cc = 0; cc < 4; ++cc) acc[j2][cc] = 0.f;

            #pragma unroll 4
            for (int h4 = 0; h4 < 16; ++h4) {
                float4 wv[4];
                #pragma unroll
                for (int j = 0; j < 4; ++j)
                    wv[j] = *(const float4*)(outw + (h4*4+j)*128 + c4);
                #pragma unroll
                for (int j2 = 0; j2 < 4; ++j2) {
                    float4 av = *(const float4*)(&sblk[b][prow + j2][h4*4]);
                    acc[j2][0] += av.x*wv[0].x + av.y*wv[1].x + av.z*wv[2].x + av.w*wv[3].x;
                    acc[j2][1] += av.x*wv[0].y + av.y*wv[1].y + av.z*wv[2].y + av.w*wv[3].y;
                    acc[j2][2] += av.x*wv[0].z + av.y*wv[1].z + av.z*wv[2].z + av.w*wv[3].z;
                    acc[j2][3] += av.x*wv[0].w + av.y*wv[1].w + av.z*wv[2].w + av.w*wv[3].w;
                }
            }

            #pragma unroll
            for (int j2 = 0; j2 < 4; ++j2) {
                size_t pos = (size_t)(pos0 + prow + j2);
                ushort4 gv = *(const ushort4*)(gsig + pos*128 + c4);
                float4 res;
                res.x = bf2f(gv.x) * (acc[j2][0] + ob.x);
                res.y = bf2f(gv.y) * (acc[j2][1] + ob.y);
                res.z = bf2f(gv.z) * (acc[j2][2] + ob.z);
                res.w = bf2f(gv.w) * (acc[j2][3] + ob.w);
                *(float4*)(out + pos*128 + c4) = res;
            }
        }
    }
}

extern "C" void kernel_launch(void* const* d_in, const int* in_sizes, int n_in,
                              void* d_out, int out_size, void* d_ws, size_t ws_size,
                              hipStream_t stream) {
    const float* z    = (const float*)d_in[0];
    const float* mask = (const float*)d_in[1];
    const float* lnw  = (const float*)d_in[2];
    const float* lnb  = (const float*)d_in[3];
    const float* lnhw = (const float*)d_in[4];
    const float* lnhb = (const float*)d_in[5];
    const float* g1w  = (const float*)d_in[6];
    const float* g1b  = (const float*)d_in[7];
    const float* g2w  = (const float*)d_in[8];
    const float* g2b  = (const float*)d_in[9];
    const float* l1w  = (const float*)d_in[10];
    const float* l1b  = (const float*)d_in[11];
    const float* l2w  = (const float*)d_in[12];
    const float* l2b  = (const float*)d_in[13];
    const float* egw  = (const float*)d_in[14];
    const float* egb  = (const float*)d_in[15];
    const float* outw = (const float*)d_in[16];
    const float* outb = (const float*)d_in[17];

    char* ws = (char*)d_ws;
    const size_t SZ_AB = (size_t)2*64*CH*2;          // 58,720,256 B (ab1+ab2, padded rows)
    const size_t SZ_G  = (size_t)NN*128*2;           // 51,380,224 B
    const size_t SZ_BL = (size_t)64*NN*4;            // 51,380,224 B
    ushort* abt    = (ushort*)ws;
    ushort* abtt   = (ushort*)(ws + SZ_AB);
    ushort* gsig   = (ushort*)(ws + 2*SZ_AB);
    float*  blkb   = (float*) (ws + 2*SZ_AB + SZ_G);
    ushort* wfrag  = (ushort*)(ws + 2*SZ_AB + SZ_G + SZ_BL);

    k_prep<<<32, 256, 0, stream>>>(g1w, l1w, g2w, l2w, egw, wfrag);
    k_proj<<<6272, 64, 0, stream>>>(z, mask, lnw, lnb, g1b, l1b, g2b, l2b, egb, wfrag, abt, gsig);
    k_transpose<<<128*49, 256, 0, stream>>>(abt, abtt);
    k_tri<<<64*16, 256, 0, stream>>>(abt, abtt, blkb);
    k_out<<<NN/256, 256, 0, stream>>>(blkb, gsig, lnhw, lnhb, outw, outb, (float*)d_out);
}

// Round 16
// 289.745 us; speedup vs baseline: 1.0875x; 1.0355x over previous
//
#include <hip/hip_runtime.h>
#include <stdint.h>

#define N 448
#define NN (N*N)          // 200704
#define P 128
#define H 64
#define PN 512            // padded row count for einsum operands
#define CH (PN*N)         // elements per channel matrix = 229376

typedef __attribute__((ext_vector_type(8))) short bf16x8;
typedef __attribute__((ext_vector_type(4))) float f32x4;
typedef __attribute__((ext_vector_type(16))) float f32x16;

__device__ __forceinline__ ushort f2bf(float f) {
    uint u = __builtin_bit_cast(uint, f);
    uint r = u + 0x7FFFu + ((u >> 16) & 1u);
    return (ushort)(r >> 16);
}
__device__ __forceinline__ float bf2f(ushort h) {
    uint u = ((uint)h) << 16;
    return __builtin_bit_cast(float, u);
}
__device__ __forceinline__ float sigmoidf(float x) {
    return 1.0f / (1.0f + __expf(-x));
}
// packed f32->bf16 RNE convert, 1 inst per 2 values (gfx950)
__device__ __forceinline__ uint cvtpk(float lo, float hi) {
    uint r;
    asm("v_cvt_pk_bf16_f32 %0, %1, %2" : "=v"(r) : "v"(lo), "v"(hi));
    return r;
}

// ---------------- kernel 0: weight prep ----------------
// wfrag layout: [(ct*4+ks)*64 + lane]*8 + b  holds Wcat[k][col], bf16
//   k = ks*32 + 8*(lane>>4) + b ; col = ct*16 + (lane&15)
// Wcat cols: 0-63 g1 | 64-127 l1 | 128-191 g2 | 192-255 l2 | 256-383 eg
__global__ void k_prep(const float* __restrict__ g1w, const float* __restrict__ l1w,
                       const float* __restrict__ g2w, const float* __restrict__ l2w,
                       const float* __restrict__ egw,
                       ushort* __restrict__ wfrag) {
    int idx = blockIdx.x*256 + threadIdx.x;
    for (int e = idx; e < 24*4*64*8; e += gridDim.x*256) {
        int b  = e & 7;
        int l  = (e >> 3) & 63;
        int ks = (e >> 9) & 3;
        int ct = e >> 11;
        int k   = ks*32 + 8*(l>>4) + b;
        int col = ct*16 + (l & 15);
        float v;
        if (col < 64)       v = g1w[k*64 + col];
        else if (col < 128) v = l1w[k*64 + col - 64];
        else if (col < 192) v = g2w[k*64 + col - 128];
        else if (col < 256) v = l2w[k*64 + col - 192];
        else                v = egw[k*128 + col - 256];
        wfrag[e] = f2bf(v);
    }
}

// ---------------- kernel 1: LN + projections -> ab1/ab2 (bf16, [c][i][j]) + g_sig ----------------
// Round-13 structure: LDS-staged ab tile -> channel-row-contiguous flush.
__global__ __launch_bounds__(256) void k_proj(
    const float* __restrict__ z, const float* __restrict__ mask,
    const float* __restrict__ lnw, const float* __restrict__ lnb,
    const float* __restrict__ g1b, const float* __restrict__ l1b,
    const float* __restrict__ g2b, const float* __restrict__ l2b,
    const float* __restrict__ egb,
    const ushort* __restrict__ wfrag,
    ushort* __restrict__ abt, ushort* __restrict__ gsig)
{
    __shared__ ushort zn[64*128];        // LN'ed tile, XOR-swizzled; reused as gs tile
    __shared__ ushort abstage[128*72];   // ab tile [chan 0-63=ab1,64-127=ab2][j], rows padded to 72
    const int t = threadIdx.x;
    const int w = t >> 6, l = t & 63;
    const int i = blockIdx.x / 7, j0 = (blockIdx.x % 7) * 64;

    // --- LN phase: 4 lanes per position, each owns 32 channels ---
    {
        const int p = t >> 2;          // 0..63 local position
        const int q = t & 3;           // channel quarter
        const float* zp = z + (size_t)(i*N + j0 + p)*P + q*32;
        float4 v[8];
        #pragma unroll
        for (int x = 0; x < 8; ++x) v[x] = *(const float4*)(zp + x*4);
        float s = 0.f, sq = 0.f;
        #pragma unroll
        for (int x = 0; x < 8; ++x) {
            s  += v[x].x + v[x].y + v[x].z + v[x].w;
            sq += v[x].x*v[x].x + v[x].y*v[x].y + v[x].z*v[x].z + v[x].w*v[x].w;
        }
        s += __shfl_xor(s, 1);  sq += __shfl_xor(sq, 1);
        s += __shfl_xor(s, 2);  sq += __shfl_xor(sq, 2);
        float mu   = s * (1.0f/128.0f);
        float var  = sq * (1.0f/128.0f) - mu*mu;
        float rstd = rsqrtf(var + 1e-5f);
        #pragma unroll
        for (int cc = 0; cc < 4; ++cc) {
            int chunk = q*4 + cc;              // 16B chunk index, channels chunk*8..+7
            const float* lwp = lnw + chunk*8;
            const float* lbp = lnb + chunk*8;
            float4 lwa = *(const float4*)(lwp), lwb = *(const float4*)(lwp+4);
            float4 lba = *(const float4*)(lbp), lbb = *(const float4*)(lbp+4);
            float4 va = v[cc*2], vb = v[cc*2+1];
            float n0 = (va.x - mu)*rstd*lwa.x + lba.x;
            float n1 = (va.y - mu)*rstd*lwa.y + lba.y;
            float n2 = (va.z - mu)*rstd*lwa.z + lba.z;
            float n3 = (va.w - mu)*rstd*lwa.w + lba.w;
            float n4 = (vb.x - mu)*rstd*lwb.x + lbb.x;
            float n5 = (vb.y - mu)*rstd*lwb.y + lbb.y;
            float n6 = (vb.z - mu)*rstd*lwb.z + lbb.z;
            float n7 = (vb.w - mu)*rstd*lwb.w + lbb.w;
            uint4 pk;
            pk.x = cvtpk(n0, n1);
            pk.y = cvtpk(n2, n3);
            pk.z = cvtpk(n4, n5);
            pk.w = cvtpk(n6, n7);
            uint boff = (uint)p*256u + (((uint)(chunk ^ (p & 7)) & 15u) << 4);
            *(uint4*)((char*)zn + boff) = pk;
        }
    }
    __syncthreads();

    const int half = w & 1, pair = w >> 1;   // pair 0 -> ab1 (g1/l1), 1 -> ab2 (g2/l2)
    const uint lr = l & 15, lk = l >> 4;
    const float* mrow = mask + (size_t)i*N + j0;
    const float* gb = pair ? g2b : g1b;
    const float* lb = pair ? l2b : l1b;

    // hoisted mask values (same across all sub-passes)
    float4 mv4[4];
    #pragma unroll
    for (int mi = 0; mi < 4; ++mi) mv4[mi] = *(const float4*)(mrow + mi*16 + (int)lk*4);

    // --- sub-passes: (gate_s, lin_s) for s=0,1 ; results -> abstage (LDS) ---
    #pragma unroll 1
    for (int sub = 0; sub < 2; ++sub) {
        const int ctg = pair*8 + half*2 + sub;   // gate tile
        const int ctl = ctg + 4;                 // lin tile
        f32x4 ag[4], al[4];
        #pragma unroll
        for (int mi = 0; mi < 4; ++mi) { ag[mi] = (f32x4){0,0,0,0}; al[mi] = (f32x4){0,0,0,0}; }

        #pragma unroll
        for (int ks = 0; ks < 4; ++ks) {
            bf16x8 bg  = *(const bf16x8*)(wfrag + ((size_t)(ctg*4 + ks)*64 + l)*8);
            bf16x8 blf = *(const bf16x8*)(wfrag + ((size_t)(ctl*4 + ks)*64 + l)*8);
            #pragma unroll
            for (int mi = 0; mi < 4; ++mi) {
                uint row = mi*16u + lr;
                uint chunk = (uint)(ks*4) + lk;
                bf16x8 af = *(const bf16x8*)((const char*)zn + row*256u + (((chunk ^ (row & 7u)) & 15u) << 4));
                ag[mi] = __builtin_amdgcn_mfma_f32_16x16x32_bf16(af, bg,  ag[mi], 0,0,0);
                al[mi] = __builtin_amdgcn_mfma_f32_16x16x32_bf16(af, blf, al[mi], 0,0,0);
            }
        }

        const int cidx = (half*2 + sub)*16 + (int)lr;    // 0..63 within ab
        const float gbias = gb[cidx];
        const float lbias = lb[cidx];
        const int srow = pair*64 + cidx;                 // abstage row
        #pragma unroll
        for (int mi = 0; mi < 4; ++mi) {
            float4 mv = mv4[mi];
            float o0 = sigmoidf(ag[mi][0] + gbias) * (al[mi][0] + lbias) * mv.x;
            float o1 = sigmoidf(ag[mi][1] + gbias) * (al[mi][1] + lbias) * mv.y;
            float o2 = sigmoidf(ag[mi][2] + gbias) * (al[mi][2] + lbias) * mv.z;
            float o3 = sigmoidf(ag[mi][3] + gbias) * (al[mi][3] + lbias) * mv.w;
            uint2 pk;
            pk.x = cvtpk(o0, o1);
            pk.y = cvtpk(o2, o3);
            *(uint2*)(abstage + (size_t)srow*72 + mi*16 + (int)lk*4) = pk;
        }
    }
    __syncthreads();   // abstage complete; zn reads for ab done

    // --- coalesced ab flush: thread -> one 64B contiguous run in one channel plane ---
    {
        int r = t >> 1, hh2 = t & 1;
        const ushort* sp = abstage + (size_t)r*72 + hh2*32;
        ushort* dp = abt + (size_t)r*CH + (size_t)i*N + j0 + hh2*32;
        #pragma unroll
        for (int k2 = 0; k2 < 4; ++k2) {
            uint4 vv = *(const uint4*)(sp + k2*8);
            *(uint4*)(dp + k2*8) = vv;
        }
    }

    // --- sub-pass 3: eg (2 tiles), overlaps the flush stores ---
    {
        f32x4 ae[4][2];
        #pragma unroll
        for (int mi = 0; mi < 4; ++mi) { ae[mi][0] = (f32x4){0,0,0,0}; ae[mi][1] = (f32x4){0,0,0,0}; }

        #pragma unroll
        for (int ks = 0; ks < 4; ++ks) {
            bf16x8 b0 = *(const bf16x8*)(wfrag + ((size_t)((16 + w*2)*4 + ks)*64 + l)*8);
            bf16x8 b1 = *(const bf16x8*)(wfrag + ((size_t)((17 + w*2)*4 + ks)*64 + l)*8);
            #pragma unroll
            for (int mi = 0; mi < 4; ++mi) {
                uint row = mi*16u + lr;
                uint chunk = (uint)(ks*4) + lk;
                bf16x8 af = *(const bf16x8*)((const char*)zn + row*256u + (((chunk ^ (row & 7u)) & 15u) << 4));
                ae[mi][0] = __builtin_amdgcn_mfma_f32_16x16x32_bf16(af, b0, ae[mi][0], 0,0,0);
                ae[mi][1] = __builtin_amdgcn_mfma_f32_16x16x32_bf16(af, b1, ae[mi][1], 0,0,0);
            }
        }

        // all waves done reading zn -> safe to overwrite it with the gs tile
        __syncthreads();

        float biasB[2];
        biasB[0] = egb[w*32 + (int)lr];
        biasB[1] = egb[w*32 + 16 + (int)lr];
        #pragma unroll
        for (int mi = 0; mi < 4; ++mi) {
            float4 mv = mv4[mi];
            float mva[4] = { mv.x, mv.y, mv.z, mv.w };
            #pragma unroll
            for (int e = 0; e < 2; ++e) {
                uint cg = (uint)(w*32 + e*16) + lr;   // 0..127
                #pragma unroll
                for (int r = 0; r < 4; ++r) {
                    float sg = sigmoidf(ae[mi][e][r] + biasB[e]) * mva[r];   // mask folded in
                    uint row = (uint)(mi*16) + lk*4u + (uint)r;
                    uint boff = row*256u + (((((cg >> 3) ^ (row & 7u)) & 15u)) << 4) + ((cg & 7u) << 1);
                    *(ushort*)((char*)zn + boff) = (ushort)cvtpk(sg, sg);
                }
            }
        }
    }
    __syncthreads();

    // coalesced gsig store: thread covers 32 channels of one position
    {
        int p2 = t >> 2, q2 = t & 3;
        size_t pos = (size_t)(i*N + j0 + p2);
        #pragma unroll
        for (int s2 = 0; s2 < 4; ++s2) {
            int chunk = q2*4 + s2;
            uint boff = (uint)p2*256u + (((uint)(chunk ^ (p2 & 7)) & 15u) << 4);
            uint4 vv = *(const uint4*)((const char*)zn + boff);
            *(uint4*)(gsig + pos*128 + q2*32 + s2*8) = vv;
        }
    }
}

// ---------------- kernel 2: per-channel transpose [c][i][k] -> [c][k][i] ----------------
__global__ __launch_bounds__(256) void k_transpose(const ushort* __restrict__ abt,
                                                   ushort* __restrict__ abtt) {
    int bid = blockIdx.x;
    int tile = bid % 49, a = bid / 49;              // a in 0..127 (both arrays)
    int y0 = (tile / 7) * 64, x0 = (tile % 7) * 64;
    const ushort* src = abt  + (size_t)a*CH;
    ushort*       dst = abtt + (size_t)a*CH;
    __shared__ ushort tl[64][68];
    int t = threadIdx.x;
    #pragma unroll
    for (int q = 0; q < 4; ++q) {
        int f = q*1024 + t*4;
        int r = f >> 6, c4 = f & 63;
        ushort4 v = *(const ushort4*)(src + (size_t)(y0 + r)*N + x0 + c4);
        tl[r][c4] = v.x; tl[r][c4+1] = v.y; tl[r][c4+2] = v.z; tl[r][c4+3] = v.w;
    }
    __syncthreads();
    #pragma unroll
    for (int q = 0; q < 4; ++q) {
        int f = q*1024 + t*4;
        int r = f >> 6, c4 = f & 63;
        ushort4 v;
        v.x = tl[c4][r]; v.y = tl[c4+1][r]; v.z = tl[c4+2][r]; v.w = tl[c4+3][r];
        *(ushort4*)(dst + (size_t)(x0 + r)*N + y0 + c4) = v;
    }
}

// ---------------- kernel 3: triangle einsums (batched NT GEMMs, 32x32x16 bf16 MFMA) ----------------
__global__ __launch_bounds__(256) void k_tri(const ushort* __restrict__ abt,
                                             const ushort* __restrict__ abtt,
                                             float* __restrict__ blk) {
    int bid = (blockIdx.x & 7)*128 + (blockIdx.x >> 3);
    const int c = bid >> 4;
    const int tij = bid & 15;
    const int i0 = (tij >> 2) * 128, j0 = (tij & 3) * 128;
    const int t = threadIdx.x, w = t >> 6, l = t & 63;
    const int wr = w >> 1, wc = w & 1;
    const uint l31 = l & 31, kg = (uint)l >> 5;   // 32x32 fragment coords

    __shared__ ushort lds[4][128*64];   // tA1, tA2, tT1, tT2 ; rows XOR-chunk swizzled

    const ushort* basep = (w >= 2) ? abtt : abt;
    const int chan = (w & 1) ? 64 + c : c;
    const int r0   = (w & 1) ? j0 : i0;
    const ushort* sbase = basep + (size_t)chan*CH + (size_t)r0*N;

    f32x16 acc[2][2];
    #pragma unroll
    for (int a = 0; a < 2; ++a)
        #pragma unroll
        for (int b = 0; b < 2; ++b) acc[a][b] = (f32x16){0,0,0,0,0,0,0,0,0,0,0,0,0,0,0,0};

    for (int kk = 0; kk < 7; ++kk) {
        __syncthreads();
        const ushort* sb = sbase + kk*64;
        #pragma unroll
        for (int q = 0; q < 16; ++q) {
            int r  = q*8 + (l >> 3);
            int ch = (l & 7) ^ (r & 7);
            const ushort* g = sb + (size_t)r*N + ch*8;
            __builtin_amdgcn_global_load_lds(
                (const __attribute__((address_space(1))) uint*)g,
                (__attribute__((address_space(3))) uint*)(&lds[w][q*512]),
                16, 0, 0);
        }
        __syncthreads();

        #pragma unroll
        for (int ks = 0; ks < 4; ++ks) {
            const uint chunk = (uint)(ks*2) + kg;
            {
                bf16x8 aA[2], bB[2];
                #pragma unroll
                for (int x = 0; x < 2; ++x) {
                    uint rowa = (uint)wr*64u + (uint)x*32u + l31;
                    uint rowb = (uint)wc*64u + (uint)x*32u + l31;
                    aA[x] = *(const bf16x8*)((const char*)lds[0] + rowa*128u + (((chunk ^ (rowa & 7u)) & 15u) << 4));
                    bB[x] = *(const bf16x8*)((const char*)lds[1] + rowb*128u + (((chunk ^ (rowb & 7u)) & 15u) << 4));
                }
                #pragma unroll
                for (int ra = 0; ra < 2; ++ra)
                    #pragma unroll
                    for (int cb = 0; cb < 2; ++cb)
                        acc[ra][cb] = __builtin_amdgcn_mfma_f32_32x32x16_bf16(aA[ra], bB[cb], acc[ra][cb], 0,0,0);
            }
            {
                bf16x8 aA[2], bB[2];
                #pragma unroll
                for (int x = 0; x < 2; ++x) {
                    uint rowa = (uint)wr*64u + (uint)x*32u + l31;
                    uint rowb = (uint)wc*64u + (uint)x*32u + l31;
                    aA[x] = *(const bf16x8*)((const char*)lds[2] + rowa*128u + (((chunk ^ (rowa & 7u)) & 15u) << 4));
                    bB[x] = *(const bf16x8*)((const char*)lds[3] + rowb*128u + (((chunk ^ (rowb & 7u)) & 15u) << 4));
                }
                #pragma unroll
                for (int ra = 0; ra < 2; ++ra)
                    #pragma unroll
                    for (int cb = 0; cb < 2; ++cb)
                        acc[ra][cb] = __builtin_amdgcn_mfma_f32_32x32x16_bf16(aA[ra], bB[cb], acc[ra][cb], 0,0,0);
            }
        }
    }

    // D layout (32x32): col = lane&31, row = (reg&3) + 8*(reg>>2) + 4*(lane>>5)
    #pragma unroll
    for (int ra = 0; ra < 2; ++ra) {
        #pragma unroll
        for (int cb = 0; cb < 2; ++cb) {
            int jb = j0 + wc*64 + cb*32 + (int)l31;
            if (jb < N) {
                #pragma unroll
                for (int r = 0; r < 16; ++r) {
                    int ii = i0 + wr*64 + ra*32 + (r & 3) + 8*(r >> 2) + 4*(int)kg;
                    if (ii < N) blk[(size_t)c*NN + (size_t)ii*N + jb] = acc[ra][cb][r];
                }
            }
        }
    }
}

// ---------------- kernel 4: LN(block) @ out_w in fp32, 256 thr (round-10 best) ----------------
__global__ __launch_bounds__(256) void k_out(const float* __restrict__ blk,
    const ushort* __restrict__ gsig,
    const float* __restrict__ lnhw, const float* __restrict__ lnhb,
    const float* __restrict__ outw, const float* __restrict__ outb,
    float* __restrict__ out)
{
    __shared__ float sblk[64][68];     // [pos][h], 272B rows
    const int t = threadIdx.x;
    const int w = t >> 6, l = t & 63;
    const int pos0 = blockIdx.x * 64;

    // --- stage blk[h][pos0+p] -> sblk[p][h], coalesced float4 reads ---
    #pragma unroll
    for (int q = 0; q < 4; ++q) {
        int flat = q*256 + t;
        int h = flat >> 4, f4 = flat & 15;
        float4 v = *(const float4*)(blk + (size_t)h*NN + pos0 + f4*4);
        sblk[f4*4+0][h] = v.x;
        sblk[f4*4+1][h] = v.y;
        sblk[f4*4+2][h] = v.z;
        sblk[f4*4+3][h] = v.w;
    }
    __syncthreads();

    // --- LN over H=64, 4 lanes per position, fp32 in place ---
    {
        int p = w*16 + (l >> 2);
        int sub = l & 3;
        float vv[16];
        float s = 0.f, sq = 0.f;
        #pragma unroll
        for (int j = 0; j < 16; ++j) {
            float x = sblk[p][sub*16 + j];
            vv[j] = x; s += x; sq += x*x;
        }
        s += __shfl_xor(s, 1);  sq += __shfl_xor(sq, 1);
        s += __shfl_xor(s, 2);  sq += __shfl_xor(sq, 2);
        float mu   = s * (1.0f/64.0f);
        float var  = sq * (1.0f/64.0f) - mu*mu;
        float rstd = rsqrtf(var + 1e-5f);
        #pragma unroll
        for (int j = 0; j < 16; ++j) {
            float nv = (vv[j] - mu)*rstd*lnhw[sub*16+j] + lnhb[sub*16+j];
            sblk[p][sub*16 + j] = nv;
        }
    }
    __syncthreads();

    // --- fp32 matvec: thread owns 4 cols; two passes of 4 positions each ---
    const int c4 = (t & 31) * 4;      // 0..124
    const int pg = t >> 5;            // 0..7
    float4 ob = *(const float4*)(outb + c4);

    #pragma unroll 1
    for (int hh = 0; hh < 2; ++hh) {
        const int prow = hh*32 + pg*4;
        float acc[4][4];
        #pragma unroll
        for (int j2 = 0; j2 < 4; ++j2)
            #pragma unroll
            for (int cc = 0; cc < 4; ++cc) acc[j2][cc] = 0.f;

        #pragma unroll 4
        for (int h4 = 0; h4 < 16; ++h4) {
            float4 wv[4];
            #pragma unroll
            for (int j = 0; j < 4; ++j)
                wv[j] = *(const float4*)(outw + (h4*4+j)*128 + c4);   // L2-hot, broadcast across blocks
            #pragma unroll
            for (int j2 = 0; j2 < 4; ++j2) {
                float4 av = *(const float4*)(&sblk[prow + j2][h4*4]);
                acc[j2][0] += av.x*wv[0].x + av.y*wv[1].x + av.z*wv[2].x + av.w*wv[3].x;
                acc[j2][1] += av.x*wv[0].y + av.y*wv[1].y + av.z*wv[2].y + av.w*wv[3].y;
                acc[j2][2] += av.x*wv[0].z + av.y*wv[1].z + av.z*wv[2].z + av.w*wv[3].z;
                acc[j2][3] += av.x*wv[0].w + av.y*wv[1].w + av.z*wv[2].w + av.w*wv[3].w;
            }
        }

        // epilogue: gate (mask pre-folded into gsig) + bias, coalesced float4 stores
        #pragma unroll
        for (int j2 = 0; j2 < 4; ++j2) {
            size_t pos = (size_t)(pos0 + prow + j2);
            ushort4 gv = *(const ushort4*)(gsig + pos*128 + c4);
            float4 res;
            res.x = bf2f(gv.x) * (acc[j2][0] + ob.x);
            res.y = bf2f(gv.y) * (acc[j2][1] + ob.y);
            res.z = bf2f(gv.z) * (acc[j2][2] + ob.z);
            res.w = bf2f(gv.w) * (acc[j2][3] + ob.w);
            *(float4*)(out + pos*128 + c4) = res;
        }
    }
}

extern "C" void kernel_launch(void* const* d_in, const int* in_sizes, int n_in,
                              void* d_out, int out_size, void* d_ws, size_t ws_size,
                              hipStream_t stream) {
    const float* z    = (const float*)d_in[0];
    const float* mask = (const float*)d_in[1];
    const float* lnw  = (const float*)d_in[2];
    const float* lnb  = (const float*)d_in[3];
    const float* lnhw = (const float*)d_in[4];
    const float* lnhb = (const float*)d_in[5];
    const float* g1w  = (const float*)d_in[6];
    const float* g1b  = (const float*)d_in[7];
    const float* g2w  = (const float*)d_in[8];
    const float* g2b  = (const float*)d_in[9];
    const float* l1w  = (const float*)d_in[10];
    const float* l1b  = (const float*)d_in[11];
    const float* l2w  = (const float*)d_in[12];
    const float* l2b  = (const float*)d_in[13];
    const float* egw  = (const float*)d_in[14];
    const float* egb  = (const float*)d_in[15];
    const float* outw = (const float*)d_in[16];
    const float* outb = (const float*)d_in[17];

    char* ws = (char*)d_ws;
    const size_t SZ_AB = (size_t)2*64*CH*2;          // 58,720,256 B (ab1+ab2, padded rows)
    const size_t SZ_G  = (size_t)NN*128*2;           // 51,380,224 B
    const size_t SZ_BL = (size_t)64*NN*4;            // 51,380,224 B
    ushort* abt    = (ushort*)ws;
    ushort* abtt   = (ushort*)(ws + SZ_AB);
    ushort* gsig   = (ushort*)(ws + 2*SZ_AB);
    float*  blkb   = (float*) (ws + 2*SZ_AB + SZ_G);
    ushort* wfrag  = (ushort*)(ws + 2*SZ_AB + SZ_G + SZ_BL);

    k_prep<<<32, 256, 0, stream>>>(g1w, l1w, g2w, l2w, egw, wfrag);
    k_proj<<<3136, 256, 0, stream>>>(z, mask, lnw, lnb, g1b, l1b, g2b, l2b, egb, wfrag, abt, gsig);
    k_transpose<<<128*49, 256, 0, stream>>>(abt, abtt);
    k_tri<<<64*16, 256, 0, stream>>>(abt, abtt, blkb);
    k_out<<<NN/64, 256, 0, stream>>>(blkb, gsig, lnhw, lnhb, outw, outb, (float*)d_out);
}